// Round 1
// baseline (6796.856 us; speedup 1.0000x reference)
//
#include <hip/hip_runtime.h>
#include <math.h>

#define N_TOK 128   // S+1 (sentinel prepended)
#define ADIM  256
#define EDIM  512
#define BSZ   8
#define NSQ   65536 // ADIM*ADIM

struct ProjArgs {
  const float* W[7];
  const float* b[7];
};

// ---------------- projections: proj[p][b*128+i][a] = elu(h @ W_p + b_p) ----
__global__ __launch_bounds__(256) void proj_kernel(
    const float* __restrict__ x, const float* __restrict__ sentinel,
    ProjArgs args, float* __restrict__ proj)
{
  const int p  = blockIdx.y;
  const int m0 = blockIdx.x * 8;      // 8 rows per block
  const int tid = threadIdx.x;
  __shared__ float hs[8][EDIM];       // 16 KB
  #pragma unroll
  for (int q = 0; q < 16; ++q) {
    int idx = tid + q * 256;
    int r = idx >> 9;                 // /512
    int c = idx & 511;
    int m = m0 + r;
    int b = m >> 7;
    int i = m & 127;
    hs[r][c] = (i == 0) ? sentinel[c] : x[((size_t)(b * 127) + (i - 1)) * EDIM + c];
  }
  __syncthreads();
  const float* W = args.W[p];
  float bias = args.b[p][tid];
  float acc[8];
  #pragma unroll
  for (int r = 0; r < 8; ++r) acc[r] = bias;
  #pragma unroll 4
  for (int k = 0; k < EDIM; ++k) {
    float wv = W[(size_t)k * ADIM + tid];     // coalesced across threads
    #pragma unroll
    for (int r = 0; r < 8; ++r) acc[r] = fmaf(hs[r][k], wv, acc[r]);
  }
  float* outp = proj + ((size_t)p * (BSZ * N_TOK) + m0) * ADIM + tid;
  #pragma unroll
  for (int r = 0; r < 8; ++r) {
    float v = acc[r];
    v = v > 0.f ? v : expm1f(v);              // elu, alpha=1
    outp[(size_t)r * ADIM] = v;
  }
}

// ---------------- step 1: t1[m][c*256+d] = sum_a A[m][a] * U[a][c*256+d] ---
// Classic fp32 tiled GEMM: 64x64 tile, BK=16, 4x4 per thread.
#define BK 16
__global__ __launch_bounds__(256) void gemm_t1(
    const float* __restrict__ A,   // [M][256] row-major (proj_u chunk)
    const float* __restrict__ U,   // [256][65536] row-major
    float* __restrict__ C)         // [M][65536]
{
  __shared__ float As[BK][68];     // pad 64->68: keeps 16B align + no conflicts
  __shared__ float Bs[BK][64];
  const int tid = threadIdx.x;
  const int tx = tid & 15, ty = tid >> 4;
  const int m0 = blockIdx.x * 64;
  const int n0 = blockIdx.y * 64;
  float acc[4][4] = {};
  for (int kt = 0; kt < ADIM; kt += BK) {
    #pragma unroll
    for (int q = 0; q < 4; ++q) {           // A tile 64x16, store transposed
      int idx = tid + q * 256;
      int r = idx >> 4, c = idx & 15;
      As[c][r] = A[(size_t)(m0 + r) * ADIM + kt + c];
    }
    #pragma unroll
    for (int q = 0; q < 4; ++q) {           // B tile 16x64
      int idx = tid + q * 256;
      int r = idx >> 6, c = idx & 63;
      Bs[r][c] = U[(size_t)(kt + r) * NSQ + n0 + c];
    }
    __syncthreads();
    #pragma unroll
    for (int kk = 0; kk < BK; ++kk) {
      float a[4], bb[4];
      #pragma unroll
      for (int r = 0; r < 4; ++r) a[r] = As[kk][ty * 4 + r];
      #pragma unroll
      for (int c = 0; c < 4; ++c) bb[c] = Bs[kk][tx * 4 + c];
      #pragma unroll
      for (int r = 0; r < 4; ++r)
        #pragma unroll
        for (int c = 0; c < 4; ++c)
          acc[r][c] = fmaf(a[r], bb[c], acc[r][c]);
    }
    __syncthreads();
  }
  #pragma unroll
  for (int r = 0; r < 4; ++r) {
    float4 v = make_float4(acc[r][0], acc[r][1], acc[r][2], acc[r][3]);
    *(float4*)&C[(size_t)(m0 + ty * 4 + r) * NSQ + n0 + tx * 4] = v;
  }
}

// ---------------- fused steps 2+3, one WG per (b,i) ------------------------
// t2[j][d] = sum_c v[j][c] * t1_i[c][d]   (t2 lives only in LDS, 16-j tiles)
// s[j][k]  = sum_d t2[j][d] * w[k][d]
__global__ __launch_bounds__(256) void fuse_t2s(
    const float* __restrict__ t1,     // [cb*128][65536]
    const float* __restrict__ projv,  // proj base of v-branch [1024][256]
    const float* __restrict__ projw,  // proj base of w-branch
    float* __restrict__ out,          // score base [8][128][128][128]
    int b0)
{
  const int i  = blockIdx.x;          // 0..127
  const int bl = blockIdx.y;          // local b in chunk
  const int b  = b0 + bl;
  const int tid = threadIdx.x;
  const float* t1row = t1 + (size_t)(bl * N_TOK + i) * NSQ;
  const float* vbase = projv + (size_t)b * N_TOK * ADIM;
  const float* wbase = projw + (size_t)b * N_TOK * ADIM;
  float* obase = out + (size_t)(b * N_TOK + i) * N_TOK * N_TOK;

  __shared__ float vs[16][ADIM];      // 16 KB
  __shared__ float t2s[16][ADIM];     // 16 KB
  __shared__ float wsh[128][65];      // 33.3 KB (pad 64->65: 2-way aliasing, free)

  const int kk = tid & 127;
  const int jh = tid >> 7;

  for (int jt = 0; jt < 8; ++jt) {
    const int j0 = jt * 16;
    __syncthreads();                  // protect vs/t2s from previous tile
    #pragma unroll
    for (int q = 0; q < 16; ++q)
      vs[q][tid] = vbase[(size_t)(j0 + q) * ADIM + tid];
    __syncthreads();

    // phase 1: thread owns column d = tid of t2 for 16 j's
    float acc[16] = {};
    #pragma unroll 4
    for (int c = 0; c < ADIM; ++c) {
      float t1v = t1row[(size_t)c * ADIM + tid];   // coalesced, L2-hot
      #pragma unroll
      for (int j = 0; j < 16; ++j)
        acc[j] = fmaf(vs[j][c], t1v, acc[j]);      // vs broadcast
    }
    #pragma unroll
    for (int j = 0; j < 16; ++j) t2s[j][tid] = acc[j];
    __syncthreads();

    // phase 2: thread owns k = kk, 8 j's; d in 4 chunks of 64 staged in LDS
    float acc2[8] = {};
    for (int dt = 0; dt < 4; ++dt) {
      #pragma unroll
      for (int q = 0; q < 32; ++q) {
        int idx = tid + q * 256;
        int r = idx >> 6, c2 = idx & 63;
        wsh[r][c2] = wbase[(size_t)r * ADIM + dt * 64 + c2];
      }
      __syncthreads();
      #pragma unroll 8
      for (int d = 0; d < 64; ++d) {
        float wv = wsh[kk][d];
        #pragma unroll
        for (int q = 0; q < 8; ++q)
          acc2[q] = fmaf(t2s[jh * 8 + q][dt * 64 + d], wv, acc2[q]);
      }
      __syncthreads();
    }
    #pragma unroll
    for (int q = 0; q < 8; ++q)
      obase[(size_t)(j0 + jh * 8 + q) * N_TOK + kk] = acc2[q];
  }
}

// ---------------- mask passthrough -----------------------------------------
__global__ void mask_kernel(const int* __restrict__ mask, float* __restrict__ out) {
  int idx = blockIdx.x * 256 + threadIdx.x;
  if (idx < BSZ * N_TOK) {
    int b = idx >> 7, i = idx & 127;
    out[idx] = (i == 0) ? 1.0f : (float)mask[b * 127 + i - 1];
  }
}

extern "C" void kernel_launch(void* const* d_in, const int* in_sizes, int n_in,
                              void* d_out, int out_size, void* d_ws, size_t ws_size,
                              hipStream_t stream)
{
  const float* x    = (const float*)d_in[0];
  // d_in[1] = pos_tags (unused by reference)
  const int*   mask = (const int*)d_in[2];
  ProjArgs pa;
  for (int p = 0; p < 7; ++p) {
    pa.W[p] = (const float*)d_in[3 + 2 * p];
    pa.b[p] = (const float*)d_in[4 + 2 * p];
  }
  const float* Us[3] = {(const float*)d_in[17], (const float*)d_in[18],
                        (const float*)d_in[19]};
  const float* sentinel = (const float*)d_in[20];

  // workspace layout: proj (7*1024*256 f32 = 28 MB) | t1 chunk (cb*33.5 MB)
  float* proj = (float*)d_ws;
  const size_t proj_bytes = (size_t)7 * 1024 * 256 * 4;
  float* t1 = (float*)((char*)d_ws + proj_bytes);
  size_t avail = (ws_size > proj_bytes) ? ws_size - proj_bytes : 0;
  int cb = 8;                                  // batch rows per chunk
  while (cb > 1 && (size_t)cb * 128 * NSQ * 4 > avail) cb >>= 1;

  proj_kernel<<<dim3(128, 7), 256, 0, stream>>>(x, sentinel, pa, proj);

  // score -> (u, v, w) branch indices per reference:
  // sib = tri(sib_head, sib_dep, sib_dep);  cop = tri(cop_head, cop_dep, cop_head)
  // gp  = tri(gp_head, gp_head_dep, gp_dep)
  const int u_idx[3] = {0, 2, 4};
  const int v_idx[3] = {1, 3, 6};
  const int w_idx[3] = {1, 2, 5};
  float* outp = (float*)d_out;

  for (int sc = 0; sc < 3; ++sc) {
    for (int b0 = 0; b0 < BSZ; b0 += cb) {
      const float* A = proj + ((size_t)u_idx[sc] * 1024 + (size_t)b0 * 128) * ADIM;
      gemm_t1<<<dim3(cb * 2, 1024), 256, 0, stream>>>(A, Us[sc], t1);
      fuse_t2s<<<dim3(128, cb), 256, 0, stream>>>(
          t1,
          proj + (size_t)v_idx[sc] * 1024 * ADIM,
          proj + (size_t)w_idx[sc] * 1024 * ADIM,
          outp + (size_t)sc * BSZ * N_TOK * N_TOK * N_TOK,
          b0);
    }
  }
  mask_kernel<<<dim3(4), 256, 0, stream>>>(
      mask, outp + (size_t)3 * BSZ * N_TOK * N_TOK * N_TOK);
}

// Round 2
// 932.031 us; speedup vs baseline: 7.2925x; 7.2925x over previous
//
#include <hip/hip_runtime.h>
#include <math.h>

#define N_TOK 128
#define ADIM  256
#define EDIM  512
#define BSZ   8
#define NSQ   65536
#define PAD   40      // LDS tile inner dim: 32 data + 8 pad (80B row stride -> conflict-free)

typedef short bf16x8 __attribute__((ext_vector_type(8)));
typedef float f32x4  __attribute__((ext_vector_type(4)));
#define MFMA_BF16(a, b, c) __builtin_amdgcn_mfma_f32_16x16x32_bf16((a), (b), (c), 0, 0, 0)

__device__ inline short f2bf(float f) {   // RNE float -> bf16
  union { float f; unsigned u; } v; v.f = f;
  unsigned r = v.u + 0x7fff + ((v.u >> 16) & 1);
  return (short)(r >> 16);
}

struct ProjArgs {
  const float* W[7];
  const float* b[7];
};

// ---------------- projections: proj[p][b*128+i][a] = elu(h @ W_p + b_p), bf16
__global__ __launch_bounds__(256) void proj_kernel(
    const float* __restrict__ x, const float* __restrict__ sentinel,
    ProjArgs args, short* __restrict__ proj)
{
  const int p  = blockIdx.y;
  const int m0 = blockIdx.x * 8;
  const int tid = threadIdx.x;
  __shared__ float hs[8][EDIM];
  #pragma unroll
  for (int q = 0; q < 16; ++q) {
    int idx = tid + q * 256;
    int r = idx >> 9, c = idx & 511;
    int m = m0 + r, b = m >> 7, i = m & 127;
    hs[r][c] = (i == 0) ? sentinel[c] : x[((size_t)(b * 127) + (i - 1)) * EDIM + c];
  }
  __syncthreads();
  const float* W = args.W[p];
  float bias = args.b[p][tid];
  float acc[8];
  #pragma unroll
  for (int r = 0; r < 8; ++r) acc[r] = bias;
  #pragma unroll 4
  for (int k = 0; k < EDIM; ++k) {
    float wv = W[(size_t)k * ADIM + tid];
    #pragma unroll
    for (int r = 0; r < 8; ++r) acc[r] = fmaf(hs[r][k], wv, acc[r]);
  }
  short* outp = proj + ((size_t)p * (BSZ * N_TOK) + m0) * ADIM + tid;
  #pragma unroll
  for (int r = 0; r < 8; ++r) {
    float v = acc[r];
    v = v > 0.f ? v : expm1f(v);
    outp[(size_t)r * ADIM] = f2bf(v);
  }
}

// ---------------- U permute+convert: Ut[(d*256+c)][a] = bf16(U[a][c*256+d]) --
// Makes U a "B^T layout" operand ([n'][k]) AND t1 output row-major in (d,c).
__global__ __launch_bounds__(256) void permU(
    const float* __restrict__ U, short* __restrict__ Ut)
{
  __shared__ float tile[64][69];
  const int c  = blockIdx.x;
  const int a0 = blockIdx.y * 64;
  const int d0 = blockIdx.z * 64;
  const int t  = threadIdx.x;
  {
    int ar = t >> 4, ds4 = (t & 15) * 4;
    #pragma unroll
    for (int q = 0; q < 4; ++q) {
      int a = ar + q * 16;
      float4 v = *(const float4*)&U[(size_t)(a0 + a) * NSQ + c * 256 + d0 + ds4];
      tile[a][ds4] = v.x; tile[a][ds4 + 1] = v.y;
      tile[a][ds4 + 2] = v.z; tile[a][ds4 + 3] = v.w;
    }
  }
  __syncthreads();
  {
    int dr = t >> 4, as4 = (t & 15) * 4;
    #pragma unroll
    for (int q = 0; q < 4; ++q) {
      int d = dr + q * 16;
      ushort4 o;
      o.x = (unsigned short)f2bf(tile[as4 + 0][d]);
      o.y = (unsigned short)f2bf(tile[as4 + 1][d]);
      o.z = (unsigned short)f2bf(tile[as4 + 2][d]);
      o.w = (unsigned short)f2bf(tile[as4 + 3][d]);
      *(ushort4*)&Ut[((size_t)(d0 + d) * 256 + c) * 256 + a0 + as4] = o;
    }
  }
}

// ---------------- t1t[bi][d*256+c] = sum_a uproj[bi][a] * Ut[d*256+c][a] ----
// 128x128 tile, 4 waves (64x64 each), 4x4 MFMA frags, BK=32.
__global__ __launch_bounds__(256) void gemm_t1(
    const short* __restrict__ A,    // [M][256] bf16 (u-projection chunk)
    const short* __restrict__ Ut,   // [65536][256] bf16 (B^T layout)
    short* __restrict__ C)          // [M][65536] bf16 = t1t[bi][d][c]
{
  __shared__ short As[128][PAD];
  __shared__ short Bs[128][PAD];
  const int tid = threadIdx.x;
  const int wave = tid >> 6, lane = tid & 63;
  const int ln15 = lane & 15, quad = lane >> 4;
  const int m0 = blockIdx.x * 128, n0 = blockIdx.y * 128;
  const int wm = (wave & 1) * 64, wn = (wave >> 1) * 64;
  f32x4 acc[4][4] = {};
  for (int kt = 0; kt < ADIM; kt += 32) {
    __syncthreads();
    #pragma unroll
    for (int p = 0; p < 2; ++p) {
      int q = tid + p * 256;
      int r = q >> 2, s = q & 3;
      *(uint4*)&As[r][s * 8] = *(const uint4*)&A [(size_t)(m0 + r) * ADIM + kt + s * 8];
      *(uint4*)&Bs[r][s * 8] = *(const uint4*)&Ut[(size_t)(n0 + r) * ADIM + kt + s * 8];
    }
    __syncthreads();
    bf16x8 af[4], bfr[4];
    #pragma unroll
    for (int r = 0; r < 4; ++r)  af[r]  = *(bf16x8*)&As[wm + r * 16 + ln15][quad * 8];
    #pragma unroll
    for (int c2 = 0; c2 < 4; ++c2) bfr[c2] = *(bf16x8*)&Bs[wn + c2 * 16 + ln15][quad * 8];
    #pragma unroll
    for (int r = 0; r < 4; ++r)
      #pragma unroll
      for (int c2 = 0; c2 < 4; ++c2)
        acc[r][c2] = MFMA_BF16(af[r], bfr[c2], acc[r][c2]);
  }
  #pragma unroll
  for (int r = 0; r < 4; ++r)
    #pragma unroll
    for (int c2 = 0; c2 < 4; ++c2)
      #pragma unroll
      for (int e = 0; e < 4; ++e) {
        int m = m0 + wm + r * 16 + quad * 4 + e;
        int n = n0 + wn + c2 * 16 + ln15;
        C[(size_t)m * NSQ + n] = f2bf(acc[r][c2][e]);
      }
}

// ---------------- fused steps 2+3 per (b,i), MFMA --------------------------
// phase A: t2[j][d] = sum_c V[j][c] * t1_i[c][d]   (t1t gives B^T layout)
// phase B: S[j][k'] = sum_d t2[j][d] * W[k'][d]
__global__ __launch_bounds__(256) void fuse_mfma(
    const short* __restrict__ t1,     // [cb*128][65536] bf16 (rows: [d][c])
    const short* __restrict__ projv,  // [1024][256] bf16
    const short* __restrict__ projw,  // [1024][256] bf16
    float* __restrict__ out,          // score base [8][128][128][128] f32
    int b0)
{
  __shared__ short Bs[256][PAD];     // t1 tile [d][c32]  20 KB
  __shared__ short Avs[64][PAD];     // V  tile [j][c32]   5 KB
  __shared__ short Ws[128][PAD];     // W  tile [k'][d32] 10 KB
  __shared__ short t2s[64][264];     // t2 [j][d] bf16    33 KB
  const int i  = blockIdx.x;
  const int bl = blockIdx.y;
  const int b  = b0 + bl;
  const int tid = threadIdx.x;
  const int wave = tid >> 6, lane = tid & 63;
  const int ln15 = lane & 15, quad = lane >> 4;
  const short* t1row = t1 + (size_t)(bl * N_TOK + i) * NSQ;
  const size_t vb = (size_t)b * N_TOK * ADIM;
  const size_t wb = (size_t)b * N_TOK * ADIM;
  float* obase = out + (size_t)(b * N_TOK + i) * N_TOK * N_TOK;

  for (int jh = 0; jh < 2; ++jh) {
    // ---- phase A: M=64(j) x N=256(d), K=256(c); wave tile 32j x 128d
    const int wj = (wave & 1) * 32, wd = (wave >> 1) * 128;
    f32x4 acc[2][8] = {};
    for (int ct = 0; ct < ADIM; ct += 32) {
      __syncthreads();
      #pragma unroll
      for (int p = 0; p < 4; ++p) {
        int q = tid + p * 256;
        int r = q >> 2, s = q & 3;
        *(uint4*)&Bs[r][s * 8] = *(const uint4*)&t1row[(size_t)r * ADIM + ct + s * 8];
      }
      {
        int r = tid >> 2, s = tid & 3;
        *(uint4*)&Avs[r][s * 8] =
            *(const uint4*)&projv[vb + (size_t)(jh * 64 + r) * ADIM + ct + s * 8];
      }
      __syncthreads();
      bf16x8 af[2];
      #pragma unroll
      for (int fr = 0; fr < 2; ++fr)
        af[fr] = *(bf16x8*)&Avs[wj + fr * 16 + ln15][quad * 8];
      #pragma unroll
      for (int fc = 0; fc < 8; ++fc) {
        bf16x8 bfc = *(bf16x8*)&Bs[wd + fc * 16 + ln15][quad * 8];
        #pragma unroll
        for (int fr = 0; fr < 2; ++fr)
          acc[fr][fc] = MFMA_BF16(af[fr], bfc, acc[fr][fc]);
      }
    }
    __syncthreads();
    #pragma unroll
    for (int fr = 0; fr < 2; ++fr)
      #pragma unroll
      for (int fc = 0; fc < 8; ++fc)
        #pragma unroll
        for (int e = 0; e < 4; ++e)
          t2s[wj + fr * 16 + quad * 4 + e][wd + fc * 16 + ln15] = f2bf(acc[fr][fc][e]);
    __syncthreads();

    // ---- phase B: M=64(j) x N=128(k'), K=256(d); wave tile 32j x 64k'
    const int wj2 = (wave & 1) * 32, wk = (wave >> 1) * 64;
    f32x4 acc2[2][4] = {};
    for (int dt = 0; dt < ADIM; dt += 32) {
      __syncthreads();
      #pragma unroll
      for (int p = 0; p < 2; ++p) {
        int q = tid + p * 256;
        int r = q >> 2, s = q & 3;
        *(uint4*)&Ws[r][s * 8] =
            *(const uint4*)&projw[wb + (size_t)r * ADIM + dt + s * 8];
      }
      __syncthreads();
      bf16x8 a2[2], b2[4];
      #pragma unroll
      for (int fr = 0; fr < 2; ++fr)
        a2[fr] = *(bf16x8*)&t2s[wj2 + fr * 16 + ln15][dt + quad * 8];
      #pragma unroll
      for (int fc = 0; fc < 4; ++fc)
        b2[fc] = *(bf16x8*)&Ws[wk + fc * 16 + ln15][quad * 8];
      #pragma unroll
      for (int fr = 0; fr < 2; ++fr)
        #pragma unroll
        for (int fc = 0; fc < 4; ++fc)
          acc2[fr][fc] = MFMA_BF16(a2[fr], b2[fc], acc2[fr][fc]);
    }
    #pragma unroll
    for (int fr = 0; fr < 2; ++fr)
      #pragma unroll
      for (int fc = 0; fc < 4; ++fc)
        #pragma unroll
        for (int e = 0; e < 4; ++e) {
          int j  = jh * 64 + wj2 + fr * 16 + quad * 4 + e;
          int k2 = wk + fc * 16 + ln15;
          obase[(size_t)j * N_TOK + k2] = acc2[fr][fc][e];
        }
  }
}

// ---------------- mask passthrough -----------------------------------------
__global__ void mask_kernel(const int* __restrict__ mask, float* __restrict__ out) {
  int idx = blockIdx.x * 256 + threadIdx.x;
  if (idx < BSZ * N_TOK) {
    int b = idx >> 7, i = idx & 127;
    out[idx] = (i == 0) ? 1.0f : (float)mask[b * 127 + i - 1];
  }
}

extern "C" void kernel_launch(void* const* d_in, const int* in_sizes, int n_in,
                              void* d_out, int out_size, void* d_ws, size_t ws_size,
                              hipStream_t stream)
{
  const float* x    = (const float*)d_in[0];
  const int*   mask = (const int*)d_in[2];
  ProjArgs pa;
  for (int p = 0; p < 7; ++p) {
    pa.W[p] = (const float*)d_in[3 + 2 * p];
    pa.b[p] = (const float*)d_in[4 + 2 * p];
  }
  const float* Us[3] = {(const float*)d_in[17], (const float*)d_in[18],
                        (const float*)d_in[19]};
  const float* sentinel = (const float*)d_in[20];

  // workspace: proj bf16 (3.7MB, pad to 4MB) | Ut bf16 (32MB) | t1t bf16 (cb*16.75MB)
  short* proj = (short*)d_ws;
  const size_t ut_off  = 4u << 20;
  const size_t t1_off  = ut_off + ((size_t)NSQ * ADIM * 2);   // +32MB
  short* Ut = (short*)((char*)d_ws + ut_off);
  short* t1 = (short*)((char*)d_ws + t1_off);
  size_t avail = (ws_size > t1_off) ? ws_size - t1_off : 0;
  int cb = 8;
  while (cb > 1 && (size_t)cb * N_TOK * NSQ * 2 > avail) cb >>= 1;

  proj_kernel<<<dim3(128, 7), 256, 0, stream>>>(x, sentinel, pa, proj);

  const int u_idx[3] = {0, 2, 4};
  const int v_idx[3] = {1, 3, 6};
  const int w_idx[3] = {1, 2, 5};
  float* outp = (float*)d_out;

  for (int sc = 0; sc < 3; ++sc) {
    permU<<<dim3(256, 4, 4), 256, 0, stream>>>(Us[sc], Ut);
    for (int b0 = 0; b0 < BSZ; b0 += cb) {
      const short* A = proj + ((size_t)u_idx[sc] * 1024 + (size_t)b0 * N_TOK) * ADIM;
      gemm_t1<<<dim3(cb, 512), 256, 0, stream>>>(A, Ut, t1);
      fuse_mfma<<<dim3(128, cb), 256, 0, stream>>>(
          t1,
          proj + (size_t)v_idx[sc] * 1024 * ADIM,
          proj + (size_t)w_idx[sc] * 1024 * ADIM,
          outp + (size_t)sc * BSZ * N_TOK * N_TOK * N_TOK,
          b0);
    }
  }
  mask_kernel<<<dim3(4), 256, 0, stream>>>(
      mask, outp + (size_t)3 * BSZ * N_TOK * N_TOK * N_TOK);
}